// Round 4
// baseline (827.296 us; speedup 1.0000x reference)
//
#include <hip/hip_runtime.h>

#define N_NODES 20000
#define NPAIRS  10000
#define N_EDGES 320000
#define CAP     64
#define KN      15

typedef _Float16 half_t;
typedef _Float16 half2_t __attribute__((ext_vector_type(2)));
typedef float f2 __attribute__((ext_vector_type(2)));

// params float-index layout
#define P_ALPHA 0
#define P_BETA  1
#define P_IEPS2 2
#define P_HC2   16
#define P_S2TF  116
#define P_RSC2  216

// workspace byte offsets
#define OFF_CNT    0u
#define OFF_COUNTS 80000u
#define OFF_STATS  160000u        // 65 doubles (520 B)
#define OFF_NBC    160528u
#define OFF_NEIGH  240528u
#define OFF_XH     1440528u       // x_h (2.56 MB) aliases buf region
#define OFF_S2X    4000528u       // s2xh (80 KB), inside old buf region after xh
#define OFF_BUF    1440528u       // buf consumed before xh/s2xh written
#define OFF_PARAMS 6560528u

// tf_l per-template stride (halfs): dword stride 324 = 4 (mod 32)
#define TF_STRIDE 648

// ---- 16-lane reduction via DPP row_ror adds: pure VALU ----
template<int CTRL>
__device__ __forceinline__ float dpp_add(float v) {
  int s = __builtin_bit_cast(int, v);
  int r = __builtin_amdgcn_update_dpp(0, s, CTRL, 0xF, 0xF, true);
  return v + __builtin_bit_cast(float, r);
}
__device__ __forceinline__ float sum16(float v) {
  v = dpp_add<0x128>(v);   // row_ror:8
  v = dpp_add<0x124>(v);   // row_ror:4
  v = dpp_add<0x122>(v);   // row_ror:2
  v = dpp_add<0x121>(v);   // row_ror:1
  return v;
}
// ds_swizzle with immediate BitMode pattern: new_lane = ((lane&and)|or)^xor
template<int OFF>
__device__ __forceinline__ float swz(float v) {
  return __builtin_bit_cast(float,
      __builtin_amdgcn_ds_swizzle(__builtin_bit_cast(int, v), OFF));
}
// gather: d[m] = value of lane ((lane&0x10)|m)  -- per-16-group transpose read
__device__ __forceinline__ void gather10(float (&d)[10], float v) {
  d[0]=swz<0x010>(v); d[1]=swz<0x030>(v); d[2]=swz<0x050>(v); d[3]=swz<0x070>(v);
  d[4]=swz<0x090>(v); d[5]=swz<0x0B0>(v); d[6]=swz<0x0D0>(v); d[7]=swz<0x0F0>(v);
  d[8]=swz<0x110>(v); d[9]=swz<0x130>(v);
}
__device__ __forceinline__ float fdot2(half2_t a, half2_t b, float c) {
  return __builtin_amdgcn_fdot2(a, b, c, false);
}

// ---------------- kernel 1: scatter edge ids per source node ----------------
__global__ void k_scatter(const int* __restrict__ ei, int* __restrict__ cnt,
                          int* __restrict__ buf) {
  int e = blockIdx.x * blockDim.x + threadIdx.x;
  if (e >= N_EDGES) return;
  int s = ei[e];
  int slot = atomicAdd(&cnt[s], 1);
  if (slot < CAP) buf[s * CAP + slot] = e;
}

// ---- kernel 2: wave-per-node; select 15 smallest edge ids via ballot-rank --
__global__ void k_select(const int* __restrict__ ei, const int* __restrict__ cnt,
                         const int* __restrict__ buf, int* __restrict__ nbc_g,
                         int* __restrict__ neigh, int* __restrict__ counts) {
  int w = (blockIdx.x * blockDim.x + threadIdx.x) >> 6;   // node
  int lane = threadIdx.x & 63;
  if (w >= N_NODES) return;
  const int* dst = ei + N_EDGES;
  int c = cnt[w];
  int cc = c < CAP ? c : CAP;
  int e = (lane < cc) ? buf[w * CAP + lane] : 0x7fffffff;
  int nb = c < KN ? c : KN;
  bool sel;
  if (cc <= KN) {                       // wave-uniform branch
    sel = lane < cc;
  } else {
    int rank = 0;
    for (int j = 0; j < cc; j++) {      // cc is wave-uniform
      int ej = __shfl(e, j);
      rank += (ej < e) ? 1 : 0;
    }
    sel = (e != 0x7fffffff) && (rank < KN);  // edge ids distinct -> exactly 15
  }
  unsigned long long mask = __ballot(sel);
  if (sel) {
    int pos = __popcll(mask & ((1ull << lane) - 1ull));
    int d = dst[e];
    neigh[w * KN + pos] = d;
    atomicAdd(&counts[d], 1);
  }
  if (lane == 0) {
    nbc_g[w] = nb;
    atomicAdd(&counts[w], 1);                          // self row
    if (nb < KN) atomicAdd(&counts[0], KN - nb);       // masked rows read x[0]
  }
}

// --- kernel 3: weighted sums for mean(M) + x->f16 + per-node ||x~||^2 ------
__global__ void k_stats(const float* __restrict__ x, const int* __restrict__ counts,
                        double* __restrict__ stats, half_t* __restrict__ xh,
                        float* __restrict__ s2xh) {
  int lane = threadIdx.x & 63;
  int wid = threadIdx.x >> 6;
  int gw = blockIdx.x * 4 + wid;
  float accx = 0.f, acc2 = 0.f;
  for (int u = gw; u < N_NODES; u += gridDim.x * 4) {
    float w = (float)counts[u];
    float val = x[u * 64 + lane];
    half_t h = (half_t)val;
    xh[u * 64 + lane] = h;
    float hv = (float)h;
    float sq = hv * hv;
#pragma unroll
    for (int off = 32; off > 0; off >>= 1) sq += __shfl_xor(sq, off, 64);
    if (lane == 0) s2xh[u] = sq;
    accx += w * val;
    acc2 += w * val * val;
  }
#pragma unroll
  for (int off = 32; off > 0; off >>= 1) acc2 += __shfl_xor(acc2, off, 64);
  __shared__ float redx[4][64];
  __shared__ float red2[4];
  redx[wid][lane] = accx;
  if (lane == 0) red2[wid] = acc2;
  __syncthreads();
  if (threadIdx.x < 64) {
    float s = redx[0][threadIdx.x] + redx[1][threadIdx.x] +
              redx[2][threadIdx.x] + redx[3][threadIdx.x];
    atomicAdd(&stats[1 + threadIdx.x], (double)s);
  }
  if (threadIdx.x == 0)
    atomicAdd(&stats[0], (double)(red2[0] + red2[1] + red2[2] + red2[3]));
}

// --------- kernel 4: eps, alpha, hC2, s2tf, rowsumC2 ------------------------
__global__ void k_finalize(const float* __restrict__ tf, const float* __restrict__ c2,
                           const float* __restrict__ alpha0,
                           const double* __restrict__ stats, float* __restrict__ params) {
  int tid = threadIdx.x;
  if (tid < 100) {
    int t = tid / 10, mm = tid % 10;
    float h = 0.f;
    for (int r = 0; r < 10; r++) { float cv = c2[t * 100 + mm * 10 + r]; h += cv * cv; }
    params[P_HC2 + tid] = 0.1f * h;                         // hC2[t][m]
    float s2 = 0.f;
    for (int f = 0; f < 64; f++) { float v = tf[tid * 64 + f]; s2 += v * v; }
    params[P_S2TF + tid] = s2;                              // ||tf[t][m]||^2
    float rs = 0.f;
    for (int m2 = 0; m2 < 10; m2++) rs += c2[t * 100 + mm * 10 + m2];
    params[P_RSC2 + tid] = rs;                              // sum_m C2[t][r][m]
  }
  if (tid < 64) {   // wave 0: meanM via per-feature partials + shfl reduce
    float s = 0.f, s2 = 0.f;
    for (int tm = 0; tm < 100; tm++) { float v = tf[tm * 64 + tid]; s += v; s2 += v * v; }
    double inv16N = 1.0 / (double)(N_NODES * 16);
    double cross = (stats[1 + tid] * inv16N) * ((double)s / 100.0);
    double B = (double)s2 / 100.0;
    double term = B - 2.0 * cross;
#pragma unroll
    for (int off = 32; off > 0; off >>= 1) term += __shfl_xor(term, off, 64);
    if (tid == 0) {
      double A = stats[0] * inv16N;
      double meanM = A + term;
      float eps = (float)(0.05 * meanM) + 1e-6f;
      float a0 = alpha0[0];
      float alpha = 1.f / (1.f + expf(-a0));
      params[P_ALPHA] = alpha;
      params[P_BETA]  = 1.f - alpha;
      params[P_IEPS2] = 1.4426950408889634f / eps;   // log2(e)/eps
    }
  }
}

// --------- kernel 5: fused f16-M + packed exp-domain Sinkhorn + FGW dist ----
// lane = (node_s, t, k). m-dimension packed in float2 (v_pk_* ops); cross-lane
// exchanges via DPP (sums) and immediate ds_swizzle (broadcast/gather).
__global__ void __launch_bounds__(320, 2)
k_main(const half_t* __restrict__ xh, const float* __restrict__ tf_g,
       const float* __restrict__ c2_g, const int* __restrict__ nbc_g,
       const int* __restrict__ neigh_g, const float* __restrict__ params,
       const float* __restrict__ s2x_g, float* __restrict__ out) {
  __shared__ __align__(16) half_t tf_l[10 * TF_STRIDE];   // [t][m*64+f], padded
  __shared__ __align__(16) float s2tf_l[100];
  __shared__ __align__(16) float hc2_l[100];
  __shared__ __align__(16) float rsc2_l[100];

  const int tid = threadIdx.x;
  const int node_s = tid / 160;
  const int s = tid % 160;
  const int t = s >> 4;
  const int k = s & 15;
  const bool k0 = (k == 0);

  for (int i = tid; i < 6400; i += 320) {
    int tt = i / 640, rem = i - tt * 640;
    tf_l[tt * TF_STRIDE + rem] = (half_t)tf_g[i];
  }
  if (tid < 100) {
    s2tf_l[tid] = params[P_S2TF + tid];
    hc2_l[tid]  = params[P_HC2 + tid];
    rsc2_l[tid] = params[P_RSC2 + tid];
  }

  const float alpha = params[P_ALPHA];
  const float beta  = params[P_BETA];
  const float niep  = -params[P_IEPS2];   // -log2(e)/eps
  const float twoal = 2.0f * alpha;

  f2 c2row2[5];   // C2[t][min(k,9)][:] packed; persistent (used in 3 dot sites)
  {
    int kc = (k < 10) ? k : 9;
#pragma unroll
    for (int j = 0; j < 5; j++)
      c2row2[j] = *(const f2*)&c2_g[t * 100 + kc * 10 + 2 * j];
  }
  __syncthreads();

  for (int p = blockIdx.x; p < NPAIRS; p += gridDim.x) {
    const int v = 2 * p + node_s;
    const int nb = nbc_g[v];
    const int srcn = (k == 0) ? v : ((k - 1) < nb ? neigh_g[v * KN + (k - 1)] : 0);
    const float s2x = s2x_g[srcn];

    // ---- per-lane M row via f16 dot products ----
    float acc[10];
    {
      const uint4* xr = (const uint4*)(xh + (size_t)srcn * 64);
      uint4 xq[8];
#pragma unroll
      for (int c = 0; c < 8; c++) xq[c] = xr[c];
#pragma unroll
      for (int m = 0; m < 10; m++) acc[m] = 0.0f;
      const half_t* tfb = &tf_l[t * TF_STRIDE];
#pragma unroll
      for (int c = 0; c < 8; c++) {
        half2_t x0 = __builtin_bit_cast(half2_t, xq[c].x);
        half2_t x1 = __builtin_bit_cast(half2_t, xq[c].y);
        half2_t x2 = __builtin_bit_cast(half2_t, xq[c].z);
        half2_t x3 = __builtin_bit_cast(half2_t, xq[c].w);
#pragma unroll
        for (int m = 0; m < 10; m++) {
          uint4 tq = *(const uint4*)&tfb[m * 64 + c * 8];
          float a = acc[m];
          a = fdot2(__builtin_bit_cast(half2_t, tq.x), x0, a);
          a = fdot2(__builtin_bit_cast(half2_t, tq.y), x1, a);
          a = fdot2(__builtin_bit_cast(half2_t, tq.z), x2, a);
          a = fdot2(__builtin_bit_cast(half2_t, tq.w), x3, a);
          acc[m] = a;
        }
      }
    }
    const float inv = 1.0f / (float)(1 + nb);
    const float pk = (k <= nb) ? inv : 0.0f;
    const float hC1k = (k == 0) ? (float)nb * inv : ((k <= nb) ? inv : 0.0f);

    f2 Mrow2[5], cc2[5], K2[5], vv2[5];
#pragma unroll
    for (int j = 0; j < 5; j++) {
      f2 st = *(const f2*)&s2tf_l[t * 10 + 2 * j];
      f2 a2 = { acc[2 * j], acc[2 * j + 1] };
      Mrow2[j] = s2x + st - 2.0f * a2;
      cc2[j] = hC1k + *(const f2*)&hc2_l[t * 10 + 2 * j];
      vv2[j] = f2{1.0f, 1.0f};
    }
    float u = 1.0f;

    auto inner5 = [&]() {
#pragma unroll 1
      for (int it = 0; it < 5; it++) {
        f2 kv2 = K2[0] * vv2[0];
#pragma unroll
        for (int j = 1; j < 5; j++) kv2 += K2[j] * vv2[j];
        u = pk * __builtin_amdgcn_rcpf(kv2.x + kv2.y);
#pragma unroll
        for (int j = 0; j < 5; j++) {
          f2 t2 = K2[j] * u;
          float wa = sum16(t2.x), wb = sum16(t2.y);
          vv2[j] = f2{0.1f * __builtin_amdgcn_rcpf(wa),
                      0.1f * __builtin_amdgcn_rcpf(wb)};
        }
      }
    };

    // ---- outer 0: Tp = p (x) q, tmp rows uniform -> rowsum(C2) ----
    {
      const float t2c = 0.2f * ((k == 0) ? (float)nb * inv : inv);
#pragma unroll
      for (int j = 0; j < 5; j++) {
        f2 rs = *(const f2*)&rsc2_l[t * 10 + 2 * j];
        f2 gw = cc2[j] - t2c * rs;
        f2 arg = (beta * Mrow2[j] + twoal * gw) * niep;
        K2[j] = f2{__builtin_amdgcn_exp2f(arg.x), __builtin_amdgcn_exp2f(arg.y)};
      }
    }
    inner5();

    // ---- outers 1,2: recompute K from current Tp, then 5 iters ----
#pragma unroll 1
    for (int o = 0; o < 2; o++) {
      float tkv[10], S[10], t0[10];
#pragma unroll
      for (int j = 0; j < 5; j++) {
        f2 b = K2[j] * vv2[j] * u;
        tkv[2 * j] = b.x; tkv[2 * j + 1] = b.y;
      }
#pragma unroll
      for (int m = 0; m < 10; m++) {
        S[m] = sum16(tkv[m]);
        t0[m] = swz<0x010>(tkv[m]);       // broadcast lane 0 of 16-group
      }
      f2 B2 = {0.f, 0.f}, SB2 = {0.f, 0.f};
#pragma unroll
      for (int j = 0; j < 5; j++) {
        B2 += f2{t0[2 * j], t0[2 * j + 1]} * c2row2[j];
        SB2 += f2{S[2 * j], S[2 * j + 1]} * c2row2[j];
      }
      float Bp = B2.x + B2.y, SBp = SB2.x + SB2.y;
      float Bv[10], SBv[10];
      gather10(Bv, Bp);
      gather10(SBv, SBp);
#pragma unroll
      for (int j = 0; j < 5; j++) {
        float a = k0 ? (SBv[2 * j] - Bv[2 * j]) : Bv[2 * j];
        float b = k0 ? (SBv[2 * j + 1] - Bv[2 * j + 1]) : Bv[2 * j + 1];
        f2 gw = cc2[j] - 2.0f * f2{a, b};
        f2 arg = (beta * Mrow2[j] + twoal * gw) * niep;
        K2[j] = f2{__builtin_amdgcn_exp2f(arg.x), __builtin_amdgcn_exp2f(arg.y)};
      }
      inner5();
    }

    // ---- final: Tp, gw_tens(Tp), distance ----
    {
      float tkv[10], S[10], t0[10];
#pragma unroll
      for (int j = 0; j < 5; j++) {
        f2 b = K2[j] * vv2[j] * u;
        tkv[2 * j] = b.x; tkv[2 * j + 1] = b.y;
      }
#pragma unroll
      for (int m = 0; m < 10; m++) {
        S[m] = sum16(tkv[m]);
        t0[m] = swz<0x010>(tkv[m]);
      }
      f2 B2 = {0.f, 0.f}, SB2 = {0.f, 0.f};
#pragma unroll
      for (int j = 0; j < 5; j++) {
        B2 += f2{t0[2 * j], t0[2 * j + 1]} * c2row2[j];
        SB2 += f2{S[2 * j], S[2 * j + 1]} * c2row2[j];
      }
      float Bp = B2.x + B2.y, SBp = SB2.x + SB2.y;
      float Bv[10], SBv[10];
      gather10(Bv, Bp);
      gather10(SBv, SBp);
      f2 dd2 = {0.f, 0.f};
#pragma unroll
      for (int j = 0; j < 5; j++) {
        float a = k0 ? (SBv[2 * j] - Bv[2 * j]) : Bv[2 * j];
        float b = k0 ? (SBv[2 * j + 1] - Bv[2 * j + 1]) : Bv[2 * j + 1];
        f2 gw = cc2[j] - 2.0f * f2{a, b};
        dd2 += (beta * Mrow2[j] + alpha * gw) * f2{tkv[2 * j], tkv[2 * j + 1]};
      }
      float dd = sum16(dd2.x + dd2.y);
      if (k == 0) out[v * 10 + t] = dd;
    }
  }
}

extern "C" void kernel_launch(void* const* d_in, const int* in_sizes, int n_in,
                              void* d_out, int out_size, void* d_ws, size_t ws_size,
                              hipStream_t stream) {
  const float* x  = (const float*)d_in[0];
  const int*   ei = (const int*)d_in[1];
  const float* c2 = (const float*)d_in[2];
  const float* tf = (const float*)d_in[3];
  const float* a0 = (const float*)d_in[4];
  float* out = (float*)d_out;
  char* ws = (char*)d_ws;
  int*    cnt    = (int*)(ws + OFF_CNT);
  int*    counts = (int*)(ws + OFF_COUNTS);
  double* stats  = (double*)(ws + OFF_STATS);
  int*    nbc    = (int*)(ws + OFF_NBC);
  int*    neigh  = (int*)(ws + OFF_NEIGH);
  int*    buf    = (int*)(ws + OFF_BUF);
  half_t* xh     = (half_t*)(ws + OFF_XH);     // aliases buf (written after use)
  float*  s2xh   = (float*)(ws + OFF_S2X);     // also inside old buf region
  float*  params = (float*)(ws + OFF_PARAMS);
  (void)in_sizes; (void)n_in; (void)out_size; (void)ws_size;

  hipMemsetAsync(ws, 0, 160528, stream);   // zero cnt, counts, stats
  k_scatter<<<(N_EDGES + 255) / 256, 256, 0, stream>>>(ei, cnt, buf);
  k_select<<<(N_NODES * 64 + 255) / 256, 256, 0, stream>>>(ei, cnt, buf, nbc, neigh, counts);
  k_stats<<<256, 256, 0, stream>>>(x, counts, stats, xh, s2xh);
  k_finalize<<<1, 128, 0, stream>>>(tf, c2, a0, stats, params);
  k_main<<<2500, 320, 0, stream>>>(xh, tf, c2, nbc, neigh, params, s2xh, out);
}

// Round 5
// 573.745 us; speedup vs baseline: 1.4419x; 1.4419x over previous
//
#include <hip/hip_runtime.h>

#define N_NODES 20000
#define NPAIRS  10000
#define N_EDGES 320000
#define CAP     64
#define KN      15

typedef _Float16 half_t;
typedef _Float16 half2_t __attribute__((ext_vector_type(2)));

// params float-index layout
#define P_ALPHA 0
#define P_BETA  1
#define P_IEPS2 2
#define P_HC2   16
#define P_S2TF  116
#define P_RSC2  216

// workspace byte offsets
#define OFF_CNT    0u
#define OFF_COUNTS 80000u
#define OFF_STATS  160000u        // 65 doubles (520 B)
#define OFF_NBC    160528u
#define OFF_NEIGH  240528u
#define OFF_XH     1440528u       // x_h (2.56 MB) aliases buf region
#define OFF_S2X    4000528u       // s2xh (80 KB), after xh
#define OFF_BUF    1440528u       // buf consumed before xh/s2xh written
#define OFF_PARAMS 6560528u

// tf_l per-template stride (halfs): dword stride 324 = 4 (mod 32)
#define TF_STRIDE 648

// ---- 16-lane reduction via DPP row_ror adds: pure VALU ----
template<int CTRL>
__device__ __forceinline__ float dpp_add(float v) {
  int s = __builtin_bit_cast(int, v);
  int r = __builtin_amdgcn_update_dpp(0, s, CTRL, 0xF, 0xF, true);
  return v + __builtin_bit_cast(float, r);
}
__device__ __forceinline__ float sum16(float v) {
  v = dpp_add<0x128>(v);   // row_ror:8
  v = dpp_add<0x124>(v);   // row_ror:4
  v = dpp_add<0x122>(v);   // row_ror:2
  v = dpp_add<0x121>(v);   // row_ror:1
  return v;
}
// ds_swizzle imm BitMode: new_lane = ((lane&0x10)|0) -> broadcast k=0 of 16-group
__device__ __forceinline__ float bcast16(float v) {
  return __builtin_bit_cast(float,
      __builtin_amdgcn_ds_swizzle(__builtin_bit_cast(int, v), 0x010));
}
__device__ __forceinline__ float fdot2(half2_t a, half2_t b, float c) {
  return __builtin_amdgcn_fdot2(a, b, c, false);
}

// ---------------- kernel 1: scatter edge ids per source node ----------------
__global__ void k_scatter(const int* __restrict__ ei, int* __restrict__ cnt,
                          int* __restrict__ buf) {
  int e = blockIdx.x * blockDim.x + threadIdx.x;
  if (e >= N_EDGES) return;
  int s = ei[e];
  int slot = atomicAdd(&cnt[s], 1);
  if (slot < CAP) buf[s * CAP + slot] = e;
}

// ---- kernel 2: wave-per-node; select 15 smallest edge ids via ballot-rank --
__global__ void k_select(const int* __restrict__ ei, const int* __restrict__ cnt,
                         const int* __restrict__ buf, int* __restrict__ nbc_g,
                         int* __restrict__ neigh, int* __restrict__ counts) {
  int w = (blockIdx.x * blockDim.x + threadIdx.x) >> 6;   // node
  int lane = threadIdx.x & 63;
  if (w >= N_NODES) return;
  const int* dst = ei + N_EDGES;
  int c = cnt[w];
  int cc = c < CAP ? c : CAP;
  int e = (lane < cc) ? buf[w * CAP + lane] : 0x7fffffff;
  int nb = c < KN ? c : KN;
  bool sel;
  if (cc <= KN) {
    sel = lane < cc;
  } else {
    int rank = 0;
    for (int j = 0; j < cc; j++) {      // cc is wave-uniform
      int ej = __shfl(e, j);
      rank += (ej < e) ? 1 : 0;
    }
    sel = (e != 0x7fffffff) && (rank < KN);
  }
  unsigned long long mask = __ballot(sel);
  if (sel) {
    int pos = __popcll(mask & ((1ull << lane) - 1ull));
    int d = dst[e];
    neigh[w * KN + pos] = d;
    atomicAdd(&counts[d], 1);
  }
  if (lane == 0) {
    nbc_g[w] = nb;
    atomicAdd(&counts[w], 1);
    if (nb < KN) atomicAdd(&counts[0], KN - nb);
  }
}

// --- kernel 3: weighted sums for mean(M) + x->f16 + per-node ||x~||^2 ------
__global__ void k_stats(const float* __restrict__ x, const int* __restrict__ counts,
                        double* __restrict__ stats, half_t* __restrict__ xh,
                        float* __restrict__ s2xh) {
  int lane = threadIdx.x & 63;
  int wid = threadIdx.x >> 6;
  int gw = blockIdx.x * 4 + wid;
  float accx = 0.f, acc2 = 0.f;
  for (int u = gw; u < N_NODES; u += gridDim.x * 4) {
    float w = (float)counts[u];
    float val = x[u * 64 + lane];
    half_t h = (half_t)val;
    xh[u * 64 + lane] = h;
    float hv = (float)h;
    float sq = hv * hv;
#pragma unroll
    for (int off = 32; off > 0; off >>= 1) sq += __shfl_xor(sq, off, 64);
    if (lane == 0) s2xh[u] = sq;
    accx += w * val;
    acc2 += w * val * val;
  }
#pragma unroll
  for (int off = 32; off > 0; off >>= 1) acc2 += __shfl_xor(acc2, off, 64);
  __shared__ float redx[4][64];
  __shared__ float red2[4];
  redx[wid][lane] = accx;
  if (lane == 0) red2[wid] = acc2;
  __syncthreads();
  if (threadIdx.x < 64) {
    float s = redx[0][threadIdx.x] + redx[1][threadIdx.x] +
              redx[2][threadIdx.x] + redx[3][threadIdx.x];
    atomicAdd(&stats[1 + threadIdx.x], (double)s);
  }
  if (threadIdx.x == 0)
    atomicAdd(&stats[0], (double)(red2[0] + red2[1] + red2[2] + red2[3]));
}

// --------- kernel 4: eps, alpha, hC2, s2tf, rowsumC2 ------------------------
__global__ void k_finalize(const float* __restrict__ tf, const float* __restrict__ c2,
                           const float* __restrict__ alpha0,
                           const double* __restrict__ stats, float* __restrict__ params) {
  int tid = threadIdx.x;
  if (tid < 100) {
    int t = tid / 10, mm = tid % 10;
    float h = 0.f;
    for (int r = 0; r < 10; r++) { float cv = c2[t * 100 + mm * 10 + r]; h += cv * cv; }
    params[P_HC2 + tid] = 0.1f * h;
    float s2 = 0.f;
    for (int f = 0; f < 64; f++) { float v = tf[tid * 64 + f]; s2 += v * v; }
    params[P_S2TF + tid] = s2;
    float rs = 0.f;
    for (int m2 = 0; m2 < 10; m2++) rs += c2[t * 100 + mm * 10 + m2];
    params[P_RSC2 + tid] = rs;
  }
  if (tid < 64) {
    float s = 0.f, s2 = 0.f;
    for (int tm = 0; tm < 100; tm++) { float v = tf[tm * 64 + tid]; s += v; s2 += v * v; }
    double inv16N = 1.0 / (double)(N_NODES * 16);
    double cross = (stats[1 + tid] * inv16N) * ((double)s / 100.0);
    double B = (double)s2 / 100.0;
    double term = B - 2.0 * cross;
#pragma unroll
    for (int off = 32; off > 0; off >>= 1) term += __shfl_xor(term, off, 64);
    if (tid == 0) {
      double A = stats[0] * inv16N;
      double meanM = A + term;
      float eps = (float)(0.05 * meanM) + 1e-6f;
      float a0 = alpha0[0];
      float alpha = 1.f / (1.f + expf(-a0));
      params[P_ALPHA] = alpha;
      params[P_BETA]  = 1.f - alpha;
      params[P_IEPS2] = 1.4426950408889634f / eps;
    }
  }
}

// ---- 5 exp-domain Sinkhorn iterations, two pairs interleaved for ILP ----
#define INNER5_DUAL                                                           \
  _Pragma("unroll 1") for (int it = 0; it < 5; it++) {                        \
    float kvA = 0.f, kvB = 0.f;                                               \
    _Pragma("unroll") for (int m = 0; m < 10; m++) {                          \
      kvA = fmaf(KA[m], vvA[m], kvA);                                         \
      kvB = fmaf(KB[m], vvB[m], kvB);                                         \
    }                                                                         \
    uA = pkA * __builtin_amdgcn_rcpf(kvA);                                    \
    uB = pkB * __builtin_amdgcn_rcpf(kvB);                                    \
    _Pragma("unroll") for (int m = 0; m < 10; m++) {                          \
      float wA = sum16(KA[m] * uA);                                           \
      float wB = sum16(KB[m] * uB);                                           \
      vvA[m] = 0.1f * __builtin_amdgcn_rcpf(wA);                              \
      vvB[m] = 0.1f * __builtin_amdgcn_rcpf(wB);                              \
    }                                                                         \
  }

// ---- recompute K from current Tp (one pair). tv exchange via LDS ----
#define SITE_RECOMPUTE(Kx, vvx, ux, Abx)                                      \
  {                                                                           \
    float tk[10], S[10], t0[10];                                              \
    _Pragma("unroll") for (int m = 0; m < 10; m++) tk[m] = Kx[m] * vvx[m] * ux;\
    _Pragma("unroll") for (int m = 0; m < 10; m++) {                          \
      S[m] = sum16(tk[m]); t0[m] = bcast16(tk[m]);                            \
    }                                                                         \
    float Bx = 0.f, SBx = 0.f;                                                \
    _Pragma("unroll") for (int m = 0; m < 10; m++) {                          \
      Bx = fmaf(t0[m], c2row[m], Bx); SBx = fmaf(S[m], c2row[m], SBx);        \
    }                                                                         \
    if (k < 10) { bsb_l[grp][k][0] = Bx; bsb_l[grp][k][1] = SBx; }            \
    __threadfence_block();                                                    \
    _Pragma("unroll") for (int j = 0; j < 5; j++) {                           \
      float4 bv = *(const float4*)&bsb_l[grp][2 * j][0];                      \
      float tva = k0 ? (bv.y - bv.x) : bv.x;                                  \
      float tvb = k0 ? (bv.w - bv.z) : bv.z;                                  \
      Kx[2 * j]     = __builtin_amdgcn_exp2f(fmaf(ctv, tva, Abx[2 * j]));     \
      Kx[2 * j + 1] = __builtin_amdgcn_exp2f(fmaf(ctv, tvb, Abx[2 * j + 1])); \
    }                                                                         \
    __threadfence_block();                                                    \
  }

// ---- final distance for one pair ----
#define SITE_FINAL(Kx, vvx, ux, D0x, vX)                                      \
  {                                                                           \
    float tk[10], S[10], t0[10];                                              \
    _Pragma("unroll") for (int m = 0; m < 10; m++) tk[m] = Kx[m] * vvx[m] * ux;\
    _Pragma("unroll") for (int m = 0; m < 10; m++) {                          \
      S[m] = sum16(tk[m]); t0[m] = bcast16(tk[m]);                            \
    }                                                                         \
    float Bx = 0.f, SBx = 0.f;                                                \
    _Pragma("unroll") for (int m = 0; m < 10; m++) {                          \
      Bx = fmaf(t0[m], c2row[m], Bx); SBx = fmaf(S[m], c2row[m], SBx);        \
    }                                                                         \
    if (k < 10) { bsb_l[grp][k][0] = Bx; bsb_l[grp][k][1] = SBx; }            \
    __threadfence_block();                                                    \
    float dd = 0.f;                                                           \
    _Pragma("unroll") for (int j = 0; j < 5; j++) {                           \
      float4 bv = *(const float4*)&bsb_l[grp][2 * j][0];                      \
      float tva = k0 ? (bv.y - bv.x) : bv.x;                                  \
      float tvb = k0 ? (bv.w - bv.z) : bv.z;                                  \
      dd = fmaf(fmaf(-twoal, tva, D0x[2 * j]), tk[2 * j], dd);                \
      dd = fmaf(fmaf(-twoal, tvb, D0x[2 * j + 1]), tk[2 * j + 1], dd);        \
    }                                                                         \
    __threadfence_block();                                                    \
    dd = sum16(dd);                                                           \
    if (k == 0) out[(vX) * 10 + t] = dd;                                      \
  }

// --------- kernel 5: dual-pair fused f16-M + exp Sinkhorn + FGW dist --------
__global__ void __launch_bounds__(320)
k_main(const half_t* __restrict__ xh, const float* __restrict__ tf_g,
       const float* __restrict__ c2_g, const int* __restrict__ nbc_g,
       const int* __restrict__ neigh_g, const float* __restrict__ params,
       const float* __restrict__ s2x_g, float* __restrict__ out) {
  __shared__ __align__(16) half_t tf_l[10 * TF_STRIDE];   // [t][m*64+f], padded
  __shared__ __align__(16) float rsc2_l[100];
  __shared__ __align__(16) float bsb_l[20][10][2];

  const int tid = threadIdx.x;
  const int node_s = tid / 160;
  const int s = tid % 160;
  const int t = s >> 4;
  const int k = s & 15;
  const bool k0 = (k == 0);
  const int grp = node_s * 10 + t;

  for (int i = tid; i < 6400; i += 320) {
    int tt = i / 640, rem = i - tt * 640;
    tf_l[tt * TF_STRIDE + rem] = (half_t)tf_g[i];
  }
  if (tid < 100) rsc2_l[tid] = params[P_RSC2 + tid];

  const float alpha = params[P_ALPHA];
  const float beta  = params[P_BETA];
  const float ieps2 = params[P_IEPS2];
  const float niep  = -ieps2;
  const float twoal = 2.0f * alpha;
  const float ctv   = 2.0f * twoal * ieps2;   // +4*alpha*log2e/eps
  const float cab   = 2.0f * beta * ieps2;    // -2*beta*niep
  const float cd    = -2.0f * beta;

  // per-lane persistent tables (constant across pairs)
  float F1[10], F2[10], c2row[10];
  {
    int kc = (k < 10) ? k : 9;
#pragma unroll
    for (int m = 0; m < 10; m++) {
      float hc2  = params[P_HC2 + t * 10 + m];
      float s2tf = params[P_S2TF + t * 10 + m];
      F1[m] = (beta * s2tf + twoal * hc2) * niep;
      F2[m] = beta * s2tf + alpha * hc2;
      c2row[m] = c2_g[t * 100 + kc * 10 + m];
    }
  }
  __syncthreads();

  for (int pp = blockIdx.x * 2; pp < NPAIRS; pp += gridDim.x * 2) {
    const int vA = 2 * pp + node_s;
    const int vB = 2 * (pp + 1) + node_s;
    const int nbA = nbc_g[vA];
    const int nbB = nbc_g[vB];
    const int srcA = (k == 0) ? vA : ((k - 1) < nbA ? neigh_g[vA * KN + (k - 1)] : 0);
    const int srcB = (k == 0) ? vB : ((k - 1) < nbB ? neigh_g[vB * KN + (k - 1)] : 0);
    const float s2xA = s2x_g[srcA];
    const float s2xB = s2x_g[srcB];

    // ---- dual M phase: tq LDS reads shared between pairs ----
    float accA[10], accB[10];
    {
      const uint4* xrA = (const uint4*)(xh + (size_t)srcA * 64);
      const uint4* xrB = (const uint4*)(xh + (size_t)srcB * 64);
      uint4 xqA[8], xqB[8];
#pragma unroll
      for (int c = 0; c < 8; c++) { xqA[c] = xrA[c]; xqB[c] = xrB[c]; }
#pragma unroll
      for (int m = 0; m < 10; m++) { accA[m] = 0.0f; accB[m] = 0.0f; }
      const half_t* tfb = &tf_l[t * TF_STRIDE];
#pragma unroll
      for (int c = 0; c < 8; c++) {
        half2_t a0 = __builtin_bit_cast(half2_t, xqA[c].x);
        half2_t a1 = __builtin_bit_cast(half2_t, xqA[c].y);
        half2_t a2 = __builtin_bit_cast(half2_t, xqA[c].z);
        half2_t a3 = __builtin_bit_cast(half2_t, xqA[c].w);
        half2_t b0 = __builtin_bit_cast(half2_t, xqB[c].x);
        half2_t b1 = __builtin_bit_cast(half2_t, xqB[c].y);
        half2_t b2 = __builtin_bit_cast(half2_t, xqB[c].z);
        half2_t b3 = __builtin_bit_cast(half2_t, xqB[c].w);
#pragma unroll
        for (int m = 0; m < 10; m++) {
          uint4 tq = *(const uint4*)&tfb[m * 64 + c * 8];
          half2_t t0h = __builtin_bit_cast(half2_t, tq.x);
          half2_t t1h = __builtin_bit_cast(half2_t, tq.y);
          half2_t t2h = __builtin_bit_cast(half2_t, tq.z);
          half2_t t3h = __builtin_bit_cast(half2_t, tq.w);
          float aa = accA[m];
          aa = fdot2(t0h, a0, aa); aa = fdot2(t1h, a1, aa);
          aa = fdot2(t2h, a2, aa); aa = fdot2(t3h, a3, aa);
          accA[m] = aa;
          float bb = accB[m];
          bb = fdot2(t0h, b0, bb); bb = fdot2(t1h, b1, bb);
          bb = fdot2(t2h, b2, bb); bb = fdot2(t3h, b3, bb);
          accB[m] = bb;
        }
      }
    }

    // ---- per-pair scalars ----
    const float invA = 1.0f / (float)(1 + nbA);
    const float invB = 1.0f / (float)(1 + nbB);
    const float pkA = (k <= nbA) ? invA : 0.0f;
    const float pkB = (k <= nbB) ? invB : 0.0f;
    const float hC1A = (k == 0) ? (float)nbA * invA : ((k <= nbA) ? invA : 0.0f);
    const float hC1B = (k == 0) ? (float)nbB * invB : ((k <= nbB) ? invB : 0.0f);
    const float baseA  = (beta * s2xA + twoal * hC1A) * niep;
    const float baseB  = (beta * s2xB + twoal * hC1B) * niep;
    const float base2A = beta * s2xA + alpha * hC1A;
    const float base2B = beta * s2xB + alpha * hC1B;
    const float ctmA = ctv * 0.1f * ((k == 0) ? (float)nbA * invA : invA);
    const float ctmB = ctv * 0.1f * ((k == 0) ? (float)nbB * invB : invB);

    float AbA[10], AbB[10], D0A[10], D0B[10];
#pragma unroll
    for (int m = 0; m < 10; m++) {
      AbA[m] = fmaf(cab, accA[m], F1[m] + baseA);
      AbB[m] = fmaf(cab, accB[m], F1[m] + baseB);
      D0A[m] = fmaf(cd, accA[m], F2[m] + base2A);
      D0B[m] = fmaf(cd, accB[m], F2[m] + base2B);
    }

    float KA[10], KB[10], vvA[10], vvB[10];
    float uA = 1.0f, uB = 1.0f;
#pragma unroll
    for (int m = 0; m < 10; m++) { vvA[m] = 1.0f; vvB[m] = 1.0f; }

    // ---- outer 0: Tp = p (x) q -> tv = tmpc*rowsum(C2) ----
#pragma unroll
    for (int j = 0; j < 5; j++) {
      float2 rs = *(const float2*)&rsc2_l[t * 10 + 2 * j];
      KA[2 * j]     = __builtin_amdgcn_exp2f(fmaf(ctmA, rs.x, AbA[2 * j]));
      KA[2 * j + 1] = __builtin_amdgcn_exp2f(fmaf(ctmA, rs.y, AbA[2 * j + 1]));
      KB[2 * j]     = __builtin_amdgcn_exp2f(fmaf(ctmB, rs.x, AbB[2 * j]));
      KB[2 * j + 1] = __builtin_amdgcn_exp2f(fmaf(ctmB, rs.y, AbB[2 * j + 1]));
    }
    INNER5_DUAL;

    // ---- outers 1,2 ----
    SITE_RECOMPUTE(KA, vvA, uA, AbA);
    SITE_RECOMPUTE(KB, vvB, uB, AbB);
    INNER5_DUAL;
    SITE_RECOMPUTE(KA, vvA, uA, AbA);
    SITE_RECOMPUTE(KB, vvB, uB, AbB);
    INNER5_DUAL;

    // ---- final distances ----
    SITE_FINAL(KA, vvA, uA, D0A, vA);
    SITE_FINAL(KB, vvB, uB, D0B, vB);
  }
}

extern "C" void kernel_launch(void* const* d_in, const int* in_sizes, int n_in,
                              void* d_out, int out_size, void* d_ws, size_t ws_size,
                              hipStream_t stream) {
  const float* x  = (const float*)d_in[0];
  const int*   ei = (const int*)d_in[1];
  const float* c2 = (const float*)d_in[2];
  const float* tf = (const float*)d_in[3];
  const float* a0 = (const float*)d_in[4];
  float* out = (float*)d_out;
  char* ws = (char*)d_ws;
  int*    cnt    = (int*)(ws + OFF_CNT);
  int*    counts = (int*)(ws + OFF_COUNTS);
  double* stats  = (double*)(ws + OFF_STATS);
  int*    nbc    = (int*)(ws + OFF_NBC);
  int*    neigh  = (int*)(ws + OFF_NEIGH);
  int*    buf    = (int*)(ws + OFF_BUF);
  half_t* xh     = (half_t*)(ws + OFF_XH);
  float*  s2xh   = (float*)(ws + OFF_S2X);
  float*  params = (float*)(ws + OFF_PARAMS);
  (void)in_sizes; (void)n_in; (void)out_size; (void)ws_size;

  hipMemsetAsync(ws, 0, 160528, stream);   // zero cnt, counts, stats
  k_scatter<<<(N_EDGES + 255) / 256, 256, 0, stream>>>(ei, cnt, buf);
  k_select<<<(N_NODES * 64 + 255) / 256, 256, 0, stream>>>(ei, cnt, buf, nbc, neigh, counts);
  k_stats<<<256, 256, 0, stream>>>(x, counts, stats, xh, s2xh);
  k_finalize<<<1, 128, 0, stream>>>(tf, c2, a0, stats, params);
  k_main<<<2500, 320, 0, stream>>>(xh, tf, c2, nbc, neigh, params, s2xh, out);
}

// Round 6
// 457.341 us; speedup vs baseline: 1.8089x; 1.2545x over previous
//
#include <hip/hip_runtime.h>

#define N_NODES 20000
#define NPAIRS  10000
#define N_EDGES 320000
#define CAP     64
#define KN      15

typedef _Float16 half_t;
typedef _Float16 half2_t __attribute__((ext_vector_type(2)));

// params float-index layout
#define P_ALPHA 0
#define P_BETA  1
#define P_IEPS2 2
#define P_EPS   3
#define P_HC2   16
#define P_RSC2  216
#define P_F1    316

// workspace byte offsets
#define OFF_CNT    0u
#define OFF_COUNTS 80000u
#define OFF_STATS  160000u        // 65 doubles (520 B)
#define OFF_NBC    160528u
#define OFF_NEIGH  240528u
#define OFF_XH     1440528u       // x_h (2.56 MB) aliases buf region
#define OFF_S2X    4000528u       // s2xh (80 KB), after xh
#define OFF_BUF    1440528u       // buf consumed before xh/s2xh written
#define OFF_PARAMS 6560528u

// tf_l per-template stride (halfs): dword stride 324 = 4 (mod 32)
#define TF_STRIDE 648

// ---- 16-lane reduction via DPP row_ror adds: pure VALU ----
template<int CTRL>
__device__ __forceinline__ float dpp_add(float v) {
  int s = __builtin_bit_cast(int, v);
  int r = __builtin_amdgcn_update_dpp(0, s, CTRL, 0xF, 0xF, true);
  return v + __builtin_bit_cast(float, r);
}
__device__ __forceinline__ float sum16(float v) {
  v = dpp_add<0x128>(v);   // row_ror:8
  v = dpp_add<0x124>(v);   // row_ror:4
  v = dpp_add<0x122>(v);   // row_ror:2
  v = dpp_add<0x121>(v);   // row_ror:1
  return v;
}
// ds_swizzle imm BitMode 0x010: new_lane = lane&0x10 -> broadcast k=0 of group
__device__ __forceinline__ float bcast16(float v) {
  return __builtin_bit_cast(float,
      __builtin_amdgcn_ds_swizzle(__builtin_bit_cast(int, v), 0x010));
}
__device__ __forceinline__ float fdot2(half2_t a, half2_t b, float c) {
  return __builtin_amdgcn_fdot2(a, b, c, false);
}

// ---------------- kernel 1: scatter edge ids per source node ----------------
__global__ void k_scatter(const int* __restrict__ ei, int* __restrict__ cnt,
                          int* __restrict__ buf) {
  int e = blockIdx.x * blockDim.x + threadIdx.x;
  if (e >= N_EDGES) return;
  int s = ei[e];
  int slot = atomicAdd(&cnt[s], 1);
  if (slot < CAP) buf[s * CAP + slot] = e;
}

// ---- kernel 2: wave-per-node; select 15 smallest edge ids via ballot-rank --
__global__ void k_select(const int* __restrict__ ei, const int* __restrict__ cnt,
                         const int* __restrict__ buf, int* __restrict__ nbc_g,
                         int* __restrict__ neigh, int* __restrict__ counts) {
  int w = (blockIdx.x * blockDim.x + threadIdx.x) >> 6;   // node
  int lane = threadIdx.x & 63;
  if (w >= N_NODES) return;
  const int* dst = ei + N_EDGES;
  int c = cnt[w];
  int cc = c < CAP ? c : CAP;
  int e = (lane < cc) ? buf[w * CAP + lane] : 0x7fffffff;
  int nb = c < KN ? c : KN;
  bool sel;
  if (cc <= KN) {
    sel = lane < cc;
  } else {
    int rank = 0;
    for (int j = 0; j < cc; j++) {      // cc is wave-uniform
      int ej = __shfl(e, j);
      rank += (ej < e) ? 1 : 0;
    }
    sel = (e != 0x7fffffff) && (rank < KN);
  }
  unsigned long long mask = __ballot(sel);
  if (sel) {
    int pos = __popcll(mask & ((1ull << lane) - 1ull));
    int d = dst[e];
    neigh[w * KN + pos] = d;
    atomicAdd(&counts[d], 1);
  }
  if (lane == 0) {
    nbc_g[w] = nb;
    atomicAdd(&counts[w], 1);
    if (nb < KN) atomicAdd(&counts[0], KN - nb);
  }
}

// --- kernel 3: weighted sums for mean(M) + x->f16 + per-node ||x~||^2 ------
__global__ void k_stats(const float* __restrict__ x, const int* __restrict__ counts,
                        double* __restrict__ stats, half_t* __restrict__ xh,
                        float* __restrict__ s2xh) {
  int lane = threadIdx.x & 63;
  int wid = threadIdx.x >> 6;
  int gw = blockIdx.x * 4 + wid;
  float accx = 0.f, acc2 = 0.f;
  for (int u = gw; u < N_NODES; u += gridDim.x * 4) {
    float w = (float)counts[u];
    float val = x[u * 64 + lane];
    half_t h = (half_t)val;
    xh[u * 64 + lane] = h;
    float hv = (float)h;
    float sq = hv * hv;
#pragma unroll
    for (int off = 32; off > 0; off >>= 1) sq += __shfl_xor(sq, off, 64);
    if (lane == 0) s2xh[u] = sq;
    accx += w * val;
    acc2 += w * val * val;
  }
#pragma unroll
  for (int off = 32; off > 0; off >>= 1) acc2 += __shfl_xor(acc2, off, 64);
  __shared__ float redx[4][64];
  __shared__ float red2[4];
  redx[wid][lane] = accx;
  if (lane == 0) red2[wid] = acc2;
  __syncthreads();
  if (threadIdx.x < 64) {
    float s = redx[0][threadIdx.x] + redx[1][threadIdx.x] +
              redx[2][threadIdx.x] + redx[3][threadIdx.x];
    atomicAdd(&stats[1 + threadIdx.x], (double)s);
  }
  if (threadIdx.x == 0)
    atomicAdd(&stats[0], (double)(red2[0] + red2[1] + red2[2] + red2[3]));
}

// --------- kernel 4: eps/alpha, then hC2, rowsumC2, F1 ----------------------
__global__ void k_finalize(const float* __restrict__ tf, const float* __restrict__ c2,
                           const float* __restrict__ alpha0,
                           const double* __restrict__ stats, float* __restrict__ params) {
  __shared__ float sh[4];
  int tid = threadIdx.x;
  if (tid < 64) {
    float s = 0.f, s2 = 0.f;
    for (int tm = 0; tm < 100; tm++) { float v = tf[tm * 64 + tid]; s += v; s2 += v * v; }
    double inv16N = 1.0 / (double)(N_NODES * 16);
    double cross = (stats[1 + tid] * inv16N) * ((double)s / 100.0);
    double B = (double)s2 / 100.0;
    double term = B - 2.0 * cross;
#pragma unroll
    for (int off = 32; off > 0; off >>= 1) term += __shfl_xor(term, off, 64);
    if (tid == 0) {
      double A = stats[0] * inv16N;
      double meanM = A + term;
      float eps = (float)(0.05 * meanM) + 1e-6f;
      float a0 = alpha0[0];
      float alpha = 1.f / (1.f + expf(-a0));
      params[P_ALPHA] = alpha;
      params[P_BETA]  = 1.f - alpha;
      params[P_IEPS2] = 1.4426950408889634f / eps;
      params[P_EPS]   = eps;
      sh[0] = alpha; sh[1] = 1.f - alpha; sh[2] = 1.4426950408889634f / eps;
    }
  }
  __syncthreads();
  if (tid < 100) {
    float alpha = sh[0], beta = sh[1], ieps2 = sh[2];
    int t = tid / 10, mm = tid % 10;
    float h = 0.f;
    for (int r = 0; r < 10; r++) { float cv = c2[t * 100 + mm * 10 + r]; h += cv * cv; }
    float hc2v = 0.1f * h;
    params[P_HC2 + tid] = hc2v;
    float s2 = 0.f;
    for (int f = 0; f < 64; f++) { float v = tf[tid * 64 + f]; s2 += v * v; }
    float rs = 0.f;
    for (int m2 = 0; m2 < 10; m2++) rs += c2[t * 100 + mm * 10 + m2];
    params[P_RSC2 + tid] = rs;
    params[P_F1 + tid] = (beta * s2 + 2.0f * alpha * hc2v) * (-ieps2);
  }
}

// --------- kernel 5: single-pair fused f16-M + drift-folded Sinkhorn --------
// lane = (node_s, t, k). q=0.1 folded out of the inner loop (tk' = 10*Tp
// invariant at every site; compensated via ctv*0.1 and final *0.1).
__global__ void __launch_bounds__(320, 7)
k_main(const half_t* __restrict__ xh, const float* __restrict__ tf_g,
       const float* __restrict__ c2_g, const int* __restrict__ nbc_g,
       const int* __restrict__ neigh_g, const float* __restrict__ params,
       const float* __restrict__ s2x_g, float* __restrict__ out) {
  __shared__ __align__(16) half_t tf_l[10 * TF_STRIDE];   // 12.96 KB
  __shared__ __align__(16) float hc2_l[100];
  __shared__ __align__(16) float rsc2_l[100];
  __shared__ __align__(16) float F1_l[100];
  __shared__ __align__(16) float bsb_l[20][10][2];

  const int tid = threadIdx.x;
  const int node_s = tid / 160;
  const int s = tid % 160;
  const int t = s >> 4;
  const int k = s & 15;
  const bool k0 = (k == 0);
  const int grp = node_s * 10 + t;

  for (int i = tid; i < 6400; i += 320) {
    int tt = i / 640, rem = i - tt * 640;
    tf_l[tt * TF_STRIDE + rem] = (half_t)tf_g[i];
  }
  if (tid < 100) {
    hc2_l[tid]  = params[P_HC2 + tid];
    rsc2_l[tid] = params[P_RSC2 + tid];
    F1_l[tid]   = params[P_F1 + tid];
  }

  const float alpha = params[P_ALPHA];
  const float beta  = params[P_BETA];
  const float ieps2 = params[P_IEPS2];
  const float eps   = params[P_EPS];
  const float niep  = -ieps2;
  const float twoal = 2.0f * alpha;
  const float ctv10 = 0.2f * twoal * ieps2;    // (2*twoal*ieps2) * 0.1 drift comp
  const float ctv   = 2.0f * twoal * ieps2;
  const float cab   = 2.0f * beta * ieps2;
  const float c_a2d = -eps * 0.69314718056f;   // Ab -> (beta*M + 2a*cc)
  const float twoal01 = 0.1f * twoal;

  float c2row[10];   // C2[t][min(k,9)][:] — used at 3 sites, keep in regs
  {
    int kc = (k < 10) ? k : 9;
#pragma unroll
    for (int m = 0; m < 10; m++) c2row[m] = c2_g[t * 100 + kc * 10 + m];
  }
  __syncthreads();

  const int kk = (k == 0) ? 0 : (k - 1);
  // prefetch pointer-chase chain for first pair
  int p = blockIdx.x;
  int nb = nbc_g[2 * p + node_s];
  int nbr = neigh_g[(2 * p + node_s) * KN + kk];

#pragma unroll 1
  for (; p < NPAIRS; p += gridDim.x) {
    const int v = 2 * p + node_s;
    const int srcn = (k == 0) ? v : (kk < nb ? nbr : 0);
    const float s2x = s2x_g[srcn];
    const uint4* xr = (const uint4*)(xh + (size_t)srcn * 64);
    uint4 xq[8];
#pragma unroll
    for (int c = 0; c < 8; c++) xq[c] = xr[c];

    // prefetch next pair's chain (clamped; values unused on last iteration)
    {
      int vn = 2 * (p + gridDim.x) + node_s;
      vn = vn < N_NODES ? vn : 0;
      nb = nbc_g[vn];
      nbr = neigh_g[vn * KN + kk];
    }

    // ---- per-lane M dot products ----
    float acc[10];
#pragma unroll
    for (int m = 0; m < 10; m++) acc[m] = 0.0f;
    {
      const half_t* tfb = &tf_l[t * TF_STRIDE];
#pragma unroll
      for (int c = 0; c < 8; c++) {
        half2_t x0 = __builtin_bit_cast(half2_t, xq[c].x);
        half2_t x1 = __builtin_bit_cast(half2_t, xq[c].y);
        half2_t x2 = __builtin_bit_cast(half2_t, xq[c].z);
        half2_t x3 = __builtin_bit_cast(half2_t, xq[c].w);
#pragma unroll
        for (int m = 0; m < 10; m++) {
          uint4 tq = *(const uint4*)&tfb[m * 64 + c * 8];
          float a = acc[m];
          a = fdot2(__builtin_bit_cast(half2_t, tq.x), x0, a);
          a = fdot2(__builtin_bit_cast(half2_t, tq.y), x1, a);
          a = fdot2(__builtin_bit_cast(half2_t, tq.z), x2, a);
          a = fdot2(__builtin_bit_cast(half2_t, tq.w), x3, a);
          acc[m] = a;
        }
      }
    }

    // ---- per-pair scalars (local nb for THIS pair is stale-free: use s2x path) --
    // note: nb/nbr now hold NEXT pair's values; recover this pair's nb from p
    const int nb_cur = nbc_g[v];   // L2-hot (just read) — cheap re-read
    const float inv = 1.0f / (float)(1 + nb_cur);
    const float pk = (k <= nb_cur) ? inv : 0.0f;
    const float hC1k = (k == 0) ? (float)nb_cur * inv : ((k <= nb_cur) ? inv : 0.0f);
    const float base = (beta * s2x + twoal * hC1k) * niep;
    const float ctm  = ctv * 0.1f * ((k == 0) ? (float)nb_cur * inv : inv);

    float Ab[10];
#pragma unroll
    for (int j = 0; j < 5; j++) {
      float2 f1 = *(const float2*)&F1_l[t * 10 + 2 * j];
      Ab[2 * j]     = fmaf(cab, acc[2 * j],     f1.x + base);
      Ab[2 * j + 1] = fmaf(cab, acc[2 * j + 1], f1.y + base);
    }

    float K[10], vv[10];
    float u = 1.0f;
#pragma unroll
    for (int m = 0; m < 10; m++) vv[m] = 1.0f;

    // ---- outer 0: Tp = p (x) q -> tv from rowsum(C2) ----
#pragma unroll
    for (int j = 0; j < 5; j++) {
      float2 rs = *(const float2*)&rsc2_l[t * 10 + 2 * j];
      K[2 * j]     = __builtin_amdgcn_exp2f(fmaf(ctm, rs.x, Ab[2 * j]));
      K[2 * j + 1] = __builtin_amdgcn_exp2f(fmaf(ctm, rs.y, Ab[2 * j + 1]));
    }

#pragma unroll 1
    for (int o = 0; o < 3; o++) {
      // 5 drift-folded Sinkhorn iterations
#pragma unroll 1
      for (int it = 0; it < 5; it++) {
        float kv = 0.0f;
#pragma unroll
        for (int m = 0; m < 10; m++) kv = fmaf(K[m], vv[m], kv);
        u = pk * __builtin_amdgcn_rcpf(kv);
#pragma unroll
        for (int m = 0; m < 10; m++) {
          float w = sum16(K[m] * u);
          vv[m] = __builtin_amdgcn_rcpf(w);
        }
      }
      if (o == 2) break;
      // ---- site: recompute K from current Tp (tk' = 10*Tp) ----
      {
        float B = 0.0f, SB = 0.0f;
#pragma unroll
        for (int m = 0; m < 10; m++) {
          float tk = K[m] * vv[m] * u;
          float S = sum16(tk);
          float t0 = bcast16(tk);
          B  = fmaf(t0, c2row[m], B);
          SB = fmaf(S,  c2row[m], SB);
        }
        if (k < 10) { bsb_l[grp][k][0] = B; bsb_l[grp][k][1] = SB; }
        __threadfence_block();
#pragma unroll
        for (int j = 0; j < 5; j++) {
          float4 bv = *(const float4*)&bsb_l[grp][2 * j][0];
          float tva = k0 ? (bv.y - bv.x) : bv.x;
          float tvb = k0 ? (bv.w - bv.z) : bv.z;
          K[2 * j]     = __builtin_amdgcn_exp2f(fmaf(ctv10, tva, Ab[2 * j]));
          K[2 * j + 1] = __builtin_amdgcn_exp2f(fmaf(ctv10, tvb, Ab[2 * j + 1]));
        }
        __threadfence_block();
      }
    }

    // ---- final: distance. coeff = c_a2d*Ab - alpha*cc - twoal*0.1*tv' ----
    {
      float tk[10];
      float B = 0.0f, SB = 0.0f;
#pragma unroll
      for (int m = 0; m < 10; m++) {
        tk[m] = K[m] * vv[m] * u;
        float S = sum16(tk[m]);
        float t0 = bcast16(tk[m]);
        B  = fmaf(t0, c2row[m], B);
        SB = fmaf(S,  c2row[m], SB);
      }
      if (k < 10) { bsb_l[grp][k][0] = B; bsb_l[grp][k][1] = SB; }
      __threadfence_block();
      float dd = 0.0f;
#pragma unroll
      for (int j = 0; j < 5; j++) {
        float4 bv = *(const float4*)&bsb_l[grp][2 * j][0];
        float2 h2 = *(const float2*)&hc2_l[t * 10 + 2 * j];
        float tva = k0 ? (bv.y - bv.x) : bv.x;
        float tvb = k0 ? (bv.w - bv.z) : bv.z;
        float cca = hC1k + h2.x;
        float ccb = hC1k + h2.y;
        float c1a = fmaf(alpha, cca, twoal01 * tva);
        float c1b = fmaf(alpha, ccb, twoal01 * tvb);
        float coa = fmaf(c_a2d, Ab[2 * j], -c1a);
        float cob = fmaf(c_a2d, Ab[2 * j + 1], -c1b);
        dd = fmaf(coa, tk[2 * j], dd);
        dd = fmaf(cob, tk[2 * j + 1], dd);
      }
      __threadfence_block();
      dd = sum16(dd * 0.1f);
      if (k == 0) out[v * 10 + t] = dd;
    }
  }
}

extern "C" void kernel_launch(void* const* d_in, const int* in_sizes, int n_in,
                              void* d_out, int out_size, void* d_ws, size_t ws_size,
                              hipStream_t stream) {
  const float* x  = (const float*)d_in[0];
  const int*   ei = (const int*)d_in[1];
  const float* c2 = (const float*)d_in[2];
  const float* tf = (const float*)d_in[3];
  const float* a0 = (const float*)d_in[4];
  float* out = (float*)d_out;
  char* ws = (char*)d_ws;
  int*    cnt    = (int*)(ws + OFF_CNT);
  int*    counts = (int*)(ws + OFF_COUNTS);
  double* stats  = (double*)(ws + OFF_STATS);
  int*    nbc    = (int*)(ws + OFF_NBC);
  int*    neigh  = (int*)(ws + OFF_NEIGH);
  int*    buf    = (int*)(ws + OFF_BUF);
  half_t* xh     = (half_t*)(ws + OFF_XH);
  float*  s2xh   = (float*)(ws + OFF_S2X);
  float*  params = (float*)(ws + OFF_PARAMS);
  (void)in_sizes; (void)n_in; (void)out_size; (void)ws_size;

  hipMemsetAsync(ws, 0, 160528, stream);   // zero cnt, counts, stats
  k_scatter<<<(N_EDGES + 255) / 256, 256, 0, stream>>>(ei, cnt, buf);
  k_select<<<(N_NODES * 64 + 255) / 256, 256, 0, stream>>>(ei, cnt, buf, nbc, neigh, counts);
  k_stats<<<512, 256, 0, stream>>>(x, counts, stats, xh, s2xh);
  k_finalize<<<1, 128, 0, stream>>>(tf, c2, a0, stats, params);
  k_main<<<2500, 320, 0, stream>>>(xh, tf, c2, nbc, neigh, params, s2xh, out);
}

// Round 8
// 444.619 us; speedup vs baseline: 1.8607x; 1.0286x over previous
//
#include <hip/hip_runtime.h>

#define N_NODES 20000
#define NPAIRS  10000
#define N_EDGES 320000
#define CAP     64
#define KN      15

typedef _Float16 half_t;
typedef _Float16 half2_t __attribute__((ext_vector_type(2)));

// params float-index layout
#define P_ALPHA 0
#define P_BETA  1
#define P_IEPS2 2
#define P_EPS   3
#define P_HC2   16
#define P_RSC2  216
#define P_F1    316

// workspace byte offsets
#define OFF_CNT    0u
#define OFF_COUNTS 80000u
#define OFF_STATS  160000u        // 65 doubles (520 B)
#define OFF_FLAG   160520u        // last-block-done counter (zeroed by memset)
#define OFF_NBC    160528u
#define OFF_NEIGH  240528u
#define OFF_XH     1440528u       // x_h (2.56 MB) aliases buf region: buf is
#define OFF_S2X    4000528u       //   consumed by k_select BEFORE k_stats writes
#define OFF_BUF    1440528u       //   xh/s2xh (R7 broke this ordering -> crash)
#define OFF_PARAMS 6560528u

// tf_l per-template stride (halfs): dword stride 324 = 4 (mod 32)
#define TF_STRIDE 648

// ---- 16-lane reduction via DPP row_ror adds: pure VALU ----
template<int CTRL>
__device__ __forceinline__ float dpp_add(float v) {
  int s = __builtin_bit_cast(int, v);
  int r = __builtin_amdgcn_update_dpp(0, s, CTRL, 0xF, 0xF, true);
  return v + __builtin_bit_cast(float, r);
}
__device__ __forceinline__ float sum16(float v) {
  v = dpp_add<0x128>(v);   // row_ror:8
  v = dpp_add<0x124>(v);   // row_ror:4
  v = dpp_add<0x122>(v);   // row_ror:2
  v = dpp_add<0x121>(v);   // row_ror:1
  return v;
}
// ds_swizzle imm BitMode 0x010: new_lane = lane&0x10 -> broadcast k=0 of group
__device__ __forceinline__ float bcast16(float v) {
  return __builtin_bit_cast(float,
      __builtin_amdgcn_ds_swizzle(__builtin_bit_cast(int, v), 0x010));
}
__device__ __forceinline__ float fdot2(half2_t a, half2_t b, float c) {
  return __builtin_amdgcn_fdot2(a, b, c, false);
}

// ---------------- kernel 1: scatter edge ids per source node ----------------
__global__ void k_scatter(const int* __restrict__ ei, int* __restrict__ cnt,
                          int* __restrict__ buf) {
  int e = blockIdx.x * blockDim.x + threadIdx.x;
  if (e >= N_EDGES) return;
  int s = ei[e];
  int slot = atomicAdd(&cnt[s], 1);
  if (slot < CAP) buf[s * CAP + slot] = e;
}

// ---- kernel 2: wave-per-node; select 15 smallest edge ids via ballot-rank --
__global__ void k_select(const int* __restrict__ ei, const int* __restrict__ cnt,
                         const int* __restrict__ buf, int* __restrict__ nbc_g,
                         int* __restrict__ neigh, int* __restrict__ counts) {
  int w = (blockIdx.x * blockDim.x + threadIdx.x) >> 6;   // node
  int lane = threadIdx.x & 63;
  if (w >= N_NODES) return;
  const int* dst = ei + N_EDGES;
  int c = cnt[w];
  int cc = c < CAP ? c : CAP;
  int e = (lane < cc) ? buf[w * CAP + lane] : 0x7fffffff;
  int nb = c < KN ? c : KN;
  bool sel;
  if (cc <= KN) {
    sel = lane < cc;
  } else {
    int rank = 0;
    for (int j = 0; j < cc; j++) {      // cc is wave-uniform
      int ej = __shfl(e, j);
      rank += (ej < e) ? 1 : 0;
    }
    sel = (e != 0x7fffffff) && (rank < KN);
  }
  unsigned long long mask = __ballot(sel);
  if (sel) {
    int pos = __popcll(mask & ((1ull << lane) - 1ull));
    int d = dst[e];
    neigh[w * KN + pos] = d;
    atomicAdd(&counts[d], 1);
  }
  if (lane == 0) {
    nbc_g[w] = nb;
    atomicAdd(&counts[w], 1);
    if (nb < KN) atomicAdd(&counts[0], KN - nb);
  }
}

// ---- kernel 3: x->f16 + ||x~||^2 + weighted sums + last-block finalize -----
#define STATS_BLOCKS 512
__global__ void k_stats(const float* __restrict__ x, const int* __restrict__ counts,
                        double* __restrict__ stats, int* __restrict__ flag,
                        half_t* __restrict__ xh, float* __restrict__ s2xh,
                        const float* __restrict__ tf, const float* __restrict__ c2,
                        const float* __restrict__ alpha0, float* __restrict__ params) {
  int lane = threadIdx.x & 63;
  int wid = threadIdx.x >> 6;
  int gw = blockIdx.x * 4 + wid;
  float accx = 0.f, acc2 = 0.f;
  for (int u = gw; u < N_NODES; u += STATS_BLOCKS * 4) {
    float w = (float)counts[u];
    float val = x[u * 64 + lane];
    half_t h = (half_t)val;
    xh[u * 64 + lane] = h;
    float hv = (float)h;
    float sq = hv * hv;
#pragma unroll
    for (int off = 32; off > 0; off >>= 1) sq += __shfl_xor(sq, off, 64);
    if (lane == 0) s2xh[u] = sq;
    accx += w * val;
    acc2 += w * val * val;
  }
#pragma unroll
  for (int off = 32; off > 0; off >>= 1) acc2 += __shfl_xor(acc2, off, 64);
  __shared__ float redx[4][64];
  __shared__ float red2[4];
  __shared__ int lastsh;
  redx[wid][lane] = accx;
  if (lane == 0) red2[wid] = acc2;
  __syncthreads();
  if (threadIdx.x < 64) {
    float s = redx[0][threadIdx.x] + redx[1][threadIdx.x] +
              redx[2][threadIdx.x] + redx[3][threadIdx.x];
    atomicAdd(&stats[1 + threadIdx.x], (double)s);
  }
  if (threadIdx.x == 0)
    atomicAdd(&stats[0], (double)(red2[0] + red2[1] + red2[2] + red2[3]));
  __syncthreads();
  if (threadIdx.x == 0) {
    __threadfence();
    int old = atomicAdd(flag, 1);
    lastsh = (old == STATS_BLOCKS - 1) ? 1 : 0;
  }
  __syncthreads();
  if (!lastsh) return;
  __threadfence();   // acquire: all blocks' stats atomics are visible
  // ------- finalize (runs once, in the last-finishing block) -------
  __shared__ float sh[4];
  int tid = threadIdx.x;
  if (tid < 64) {
    float s = 0.f, s2 = 0.f;
    for (int tm = 0; tm < 100; tm++) { float v = tf[tm * 64 + tid]; s += v; s2 += v * v; }
    double inv16N = 1.0 / (double)(N_NODES * 16);
    double cross = (stats[1 + tid] * inv16N) * ((double)s / 100.0);
    double B = (double)s2 / 100.0;
    double term = B - 2.0 * cross;
#pragma unroll
    for (int off = 32; off > 0; off >>= 1) term += __shfl_xor(term, off, 64);
    if (tid == 0) {
      double A = stats[0] * inv16N;
      double meanM = A + term;
      float eps = (float)(0.05 * meanM) + 1e-6f;
      float a0 = alpha0[0];
      float alpha = 1.f / (1.f + expf(-a0));
      params[P_ALPHA] = alpha;
      params[P_BETA]  = 1.f - alpha;
      params[P_IEPS2] = 1.4426950408889634f / eps;
      params[P_EPS]   = eps;
      sh[0] = alpha; sh[1] = 1.f - alpha; sh[2] = 1.4426950408889634f / eps;
    }
  }
  __syncthreads();
  if (tid < 100) {
    float alpha = sh[0], beta = sh[1], ieps2 = sh[2];
    int t = tid / 10, mm = tid % 10;
    float h = 0.f;
    for (int r = 0; r < 10; r++) { float cv = c2[t * 100 + mm * 10 + r]; h += cv * cv; }
    float hc2v = 0.1f * h;
    params[P_HC2 + tid] = hc2v;
    float s2 = 0.f;
    for (int f = 0; f < 64; f++) { float v = tf[tid * 64 + f]; s2 += v * v; }
    float rs = 0.f;
    for (int m2 = 0; m2 < 10; m2++) rs += c2[t * 100 + mm * 10 + m2];
    params[P_RSC2 + tid] = rs;
    params[P_F1 + tid] = (beta * s2 + 2.0f * alpha * hc2v) * (-ieps2);
  }
}

// --------- kernel 4: single-pair fused f16-M + drift-folded Sinkhorn --------
// lane = (node_s, t, k). q=0.1 folded out of the inner loop (tk' = 10*Tp).
// C2 rows read from LDS at sites (saves 10 persistent VGPRs); xq in 2 chunks.
__global__ void __launch_bounds__(320, 6)
k_main(const half_t* __restrict__ xh, const float* __restrict__ tf_g,
       const float* __restrict__ c2_g, const int* __restrict__ nbc_g,
       const int* __restrict__ neigh_g, const float* __restrict__ params,
       const float* __restrict__ s2x_g, float* __restrict__ out) {
  __shared__ __align__(16) half_t tf_l[10 * TF_STRIDE];   // 12.96 KB
  __shared__ __align__(16) float c2_l[1000];              // 4 KB
  __shared__ __align__(16) float hc2_l[100];
  __shared__ __align__(16) float rsc2_l[100];
  __shared__ __align__(16) float F1_l[100];
  __shared__ __align__(16) float bsb_l[20][10][2];

  const int tid = threadIdx.x;
  const int node_s = tid / 160;
  const int s = tid % 160;
  const int t = s >> 4;
  const int k = s & 15;
  const bool k0 = (k == 0);
  const int grp = node_s * 10 + t;

  for (int i = tid; i < 6400; i += 320) {
    int tt = i / 640, rem = i - tt * 640;
    tf_l[tt * TF_STRIDE + rem] = (half_t)tf_g[i];
  }
  for (int i = tid; i < 1000; i += 320) c2_l[i] = c2_g[i];
  if (tid < 100) {
    hc2_l[tid]  = params[P_HC2 + tid];
    rsc2_l[tid] = params[P_RSC2 + tid];
    F1_l[tid]   = params[P_F1 + tid];
  }

  const float alpha = params[P_ALPHA];
  const float beta  = params[P_BETA];
  const float ieps2 = params[P_IEPS2];
  const float eps   = params[P_EPS];
  const float niep  = -ieps2;
  const float twoal = 2.0f * alpha;
  const float ctv10 = 0.2f * twoal * ieps2;    // = ctv*0.1 (drift-compensated)
  const float cab   = 2.0f * beta * ieps2;
  const float c_a2d = -eps * 0.69314718056f;   // Ab -> (beta*M + 2a*cc)
  const float twoal01 = 0.1f * twoal;

  const int idx_c2 = t * 100 + ((k < 10) ? k : 9) * 10;   // C2[t][kc][*] LDS base
  __syncthreads();

  const int kk = (k == 0) ? 0 : (k - 1);
  // prefetch pointer-chase chain for first pair
  int p = blockIdx.x;
  int nb_pf = nbc_g[2 * p + node_s];
  int nbr_pf = neigh_g[(2 * p + node_s) * KN + kk];

#pragma unroll 1
  for (; p < NPAIRS; p += gridDim.x) {
    const int v = 2 * p + node_s;
    const int nb = nb_pf;
    const int srcn = (k == 0) ? v : (kk < nb ? nbr_pf : 0);
    const float s2x = s2x_g[srcn];
    const uint4* xr = (const uint4*)(xh + (size_t)srcn * 64);

    // prefetch next pair's chain (clamped; unused on last iteration)
    {
      int vn = 2 * (p + gridDim.x) + node_s;
      vn = vn < N_NODES ? vn : 0;
      nb_pf = nbc_g[vn];
      nbr_pf = neigh_g[vn * KN + kk];
    }

    // ---- per-lane M dot products (two 32B chunks to cap VGPR pressure) ----
    float acc[10];
#pragma unroll
    for (int m = 0; m < 10; m++) acc[m] = 0.0f;
    {
      const half_t* tfb = &tf_l[t * TF_STRIDE];
#pragma unroll 1
      for (int ch = 0; ch < 2; ch++) {
        uint4 xq[4];
#pragma unroll
        for (int c = 0; c < 4; c++) xq[c] = xr[ch * 4 + c];
#pragma unroll
        for (int c = 0; c < 4; c++) {
          half2_t x0 = __builtin_bit_cast(half2_t, xq[c].x);
          half2_t x1 = __builtin_bit_cast(half2_t, xq[c].y);
          half2_t x2 = __builtin_bit_cast(half2_t, xq[c].z);
          half2_t x3 = __builtin_bit_cast(half2_t, xq[c].w);
#pragma unroll
          for (int m = 0; m < 10; m++) {
            uint4 tq = *(const uint4*)&tfb[m * 64 + (ch * 4 + c) * 8];
            float a = acc[m];
            a = fdot2(__builtin_bit_cast(half2_t, tq.x), x0, a);
            a = fdot2(__builtin_bit_cast(half2_t, tq.y), x1, a);
            a = fdot2(__builtin_bit_cast(half2_t, tq.z), x2, a);
            a = fdot2(__builtin_bit_cast(half2_t, tq.w), x3, a);
            acc[m] = a;
          }
        }
      }
    }

    // ---- per-pair scalars ----
    const float inv = 1.0f / (float)(1 + nb);
    const float pk = (k <= nb) ? inv : 0.0f;
    const float hC1k = (k == 0) ? (float)nb * inv : ((k <= nb) ? inv : 0.0f);
    const float base = (beta * s2x + twoal * hC1k) * niep;
    const float ctm  = ctv10 * ((k == 0) ? (float)nb * inv : inv);  // FIXED: no 2x

    float Ab[10];
#pragma unroll
    for (int j = 0; j < 5; j++) {
      float2 f1 = *(const float2*)&F1_l[t * 10 + 2 * j];
      Ab[2 * j]     = fmaf(cab, acc[2 * j],     f1.x + base);
      Ab[2 * j + 1] = fmaf(cab, acc[2 * j + 1], f1.y + base);
    }

    float K[10], vv[10];
    float u = 1.0f;
#pragma unroll
    for (int m = 0; m < 10; m++) vv[m] = 1.0f;

    // ---- outer 0: Tp = p (x) q -> tv from rowsum(C2) ----
#pragma unroll
    for (int j = 0; j < 5; j++) {
      float2 rs = *(const float2*)&rsc2_l[t * 10 + 2 * j];
      K[2 * j]     = __builtin_amdgcn_exp2f(fmaf(ctm, rs.x, Ab[2 * j]));
      K[2 * j + 1] = __builtin_amdgcn_exp2f(fmaf(ctm, rs.y, Ab[2 * j + 1]));
    }

#pragma unroll 1
    for (int o = 0; o < 3; o++) {
      // 5 drift-folded Sinkhorn iterations
#pragma unroll 1
      for (int it = 0; it < 5; it++) {
        float kv = 0.0f;
#pragma unroll
        for (int m = 0; m < 10; m++) kv = fmaf(K[m], vv[m], kv);
        u = pk * __builtin_amdgcn_rcpf(kv);
#pragma unroll
        for (int m = 0; m < 10; m++) {
          float w = sum16(K[m] * u);
          vv[m] = __builtin_amdgcn_rcpf(w);
        }
      }
      if (o == 2) break;
      // ---- site: recompute K from current Tp (tk' = 10*Tp) ----
      {
        float B = 0.0f, SB = 0.0f;
#pragma unroll
        for (int j = 0; j < 5; j++) {
          float2 c2p = *(const float2*)&c2_l[idx_c2 + 2 * j];
          float tka = K[2 * j] * vv[2 * j] * u;
          float tkb = K[2 * j + 1] * vv[2 * j + 1] * u;
          B  = fmaf(bcast16(tka), c2p.x, B);
          SB = fmaf(sum16(tka),   c2p.x, SB);
          B  = fmaf(bcast16(tkb), c2p.y, B);
          SB = fmaf(sum16(tkb),   c2p.y, SB);
        }
        if (k < 10) { bsb_l[grp][k][0] = B; bsb_l[grp][k][1] = SB; }
        __threadfence_block();
#pragma unroll
        for (int j = 0; j < 5; j++) {
          float4 bv = *(const float4*)&bsb_l[grp][2 * j][0];
          float tva = k0 ? (bv.y - bv.x) : bv.x;
          float tvb = k0 ? (bv.w - bv.z) : bv.z;
          K[2 * j]     = __builtin_amdgcn_exp2f(fmaf(ctv10, tva, Ab[2 * j]));
          K[2 * j + 1] = __builtin_amdgcn_exp2f(fmaf(ctv10, tvb, Ab[2 * j + 1]));
        }
        __threadfence_block();
      }
    }

    // ---- final: distance. coeff = c_a2d*Ab - alpha*cc - twoal*0.1*tv' ----
    {
      float tk[10];
      float B = 0.0f, SB = 0.0f;
#pragma unroll
      for (int j = 0; j < 5; j++) {
        float2 c2p = *(const float2*)&c2_l[idx_c2 + 2 * j];
        tk[2 * j]     = K[2 * j] * vv[2 * j] * u;
        tk[2 * j + 1] = K[2 * j + 1] * vv[2 * j + 1] * u;
        B  = fmaf(bcast16(tk[2 * j]), c2p.x, B);
        SB = fmaf(sum16(tk[2 * j]),   c2p.x, SB);
        B  = fmaf(bcast16(tk[2 * j + 1]), c2p.y, B);
        SB = fmaf(sum16(tk[2 * j + 1]),   c2p.y, SB);
      }
      if (k < 10) { bsb_l[grp][k][0] = B; bsb_l[grp][k][1] = SB; }
      __threadfence_block();
      float dd = 0.0f;
#pragma unroll
      for (int j = 0; j < 5; j++) {
        float4 bv = *(const float4*)&bsb_l[grp][2 * j][0];
        float2 h2 = *(const float2*)&hc2_l[t * 10 + 2 * j];
        float tva = k0 ? (bv.y - bv.x) : bv.x;
        float tvb = k0 ? (bv.w - bv.z) : bv.z;
        float c1a = fmaf(alpha, hC1k + h2.x, twoal01 * tva);
        float c1b = fmaf(alpha, hC1k + h2.y, twoal01 * tvb);
        float coa = fmaf(c_a2d, Ab[2 * j], -c1a);
        float cob = fmaf(c_a2d, Ab[2 * j + 1], -c1b);
        dd = fmaf(coa, tk[2 * j], dd);
        dd = fmaf(cob, tk[2 * j + 1], dd);
      }
      __threadfence_block();
      dd = sum16(dd * 0.1f);
      if (k == 0) out[v * 10 + t] = dd;
    }
  }
}

extern "C" void kernel_launch(void* const* d_in, const int* in_sizes, int n_in,
                              void* d_out, int out_size, void* d_ws, size_t ws_size,
                              hipStream_t stream) {
  const float* x  = (const float*)d_in[0];
  const int*   ei = (const int*)d_in[1];
  const float* c2 = (const float*)d_in[2];
  const float* tf = (const float*)d_in[3];
  const float* a0 = (const float*)d_in[4];
  float* out = (float*)d_out;
  char* ws = (char*)d_ws;
  int*    cnt    = (int*)(ws + OFF_CNT);
  int*    counts = (int*)(ws + OFF_COUNTS);
  double* stats  = (double*)(ws + OFF_STATS);
  int*    flag   = (int*)(ws + OFF_FLAG);
  int*    nbc    = (int*)(ws + OFF_NBC);
  int*    neigh  = (int*)(ws + OFF_NEIGH);
  int*    buf    = (int*)(ws + OFF_BUF);
  half_t* xh     = (half_t*)(ws + OFF_XH);
  float*  s2xh   = (float*)(ws + OFF_S2X);
  float*  params = (float*)(ws + OFF_PARAMS);
  (void)in_sizes; (void)n_in; (void)out_size; (void)ws_size;

  hipMemsetAsync(ws, 0, 160528, stream);   // zero cnt, counts, stats, flag
  k_scatter<<<N_EDGES / 256, 256, 0, stream>>>(ei, cnt, buf);
  k_select<<<(N_NODES * 64 + 255) / 256, 256, 0, stream>>>(ei, cnt, buf, nbc, neigh, counts);
  k_stats<<<STATS_BLOCKS, 256, 0, stream>>>(x, counts, stats, flag, xh, s2xh,
                                            tf, c2, a0, params);
  k_main<<<2500, 320, 0, stream>>>(xh, tf, c2, nbc, neigh, params, s2xh, out);
}